// Round 5
// baseline (101.213 us; speedup 1.0000x reference)
//
#include <hip/hip_runtime.h>
#include <cmath>

// Local contrast normalization, streaming row-pipeline v2.
// x: [64,512,512,1] f32; 9x9 Gaussian (separable, asymmetric center 4.5),
// SAME zero padding; out = keep ? d/sqrt(conv(d^2)) : d, keep = norm > 0.5.
//
// Block = 128 threads (2 waves) = one full 512-px row, 1 float4/lane.
// Strip = 16 output rows, 32 pipeline steps (+-8-row warm-up).
// Rings: hx/h2 8-deep in registers (+ current-row bypass = 9 taps),
//        d 8-deep in LDS (padded columns -> free zero-pad, conflict-free).
// Barrier per step is lgkm-only + raw s_barrier: global loads stay in
// flight across it (the T4 "never drain vmcnt" rule); next row's xc is
// prefetched before the barrier.

struct W9 { float w[9]; };

#define HW     512
#define NF4    128      // float4 per image row
#define SROWS  16       // output rows per block
#define NSTEP  32       // SROWS + 16
#define DPITCH 130      // f4 per d-ring slot: [pad][128 cols][pad]

__device__ __forceinline__ float4 conv9_3(float4 a, float4 b, float4 c,
                                          const float* w) {
    float X[12] = {a.x, a.y, a.z, a.w, b.x, b.y, b.z, b.w, c.x, c.y, c.z, c.w};
    float4 o = {0.f, 0.f, 0.f, 0.f};
#pragma unroll
    for (int j = 0; j < 9; ++j) {
        o.x = fmaf(w[j], X[j + 0], o.x);
        o.y = fmaf(w[j], X[j + 1], o.y);
        o.z = fmaf(w[j], X[j + 2], o.z);
        o.w = fmaf(w[j], X[j + 3], o.w);
    }
    return o;
}

__device__ __forceinline__ float4 sq4(float4 a) {
    return float4{a.x * a.x, a.y * a.y, a.z * a.z, a.w * a.w};
}

__global__ __launch_bounds__(128, 4) void lcn_kernel(const float* __restrict__ x,
                                                     float* __restrict__ out,
                                                     W9 wts) {
    __shared__ float4 dring[8 * DPITCH];

    const int tid = threadIdx.x;
    // XCD swizzle: 2048 blocks = 8 XCDs x 256. Each image's 32 strips land
    // on one XCD (8 images/XCD) -> vertical-halo rows are L2-shared.
    const int p = blockIdx.x;                 // 0..2047
    const int lid = (p & 7) * 256 + (p >> 3); // bijective
    const int img = lid >> 5;                 // 0..63
    const int strip = lid & 31;               // 0..31
    const int R0 = strip * SROWS;

    const float* xb = x + (size_t)img * HW * HW;
    float* ob = out + (size_t)img * HW * HW;

    float w[9];
#pragma unroll
    for (int i = 0; i < 9; ++i) w[i] = wts.w[i];

    // zero the pad columns (f4 index 0 and 129) of all 8 ring slots, once.
    // Visible to all lanes after the step-0 barrier; first read is at s=8.
    if (tid < 16)
        dring[(tid >> 1) * DPITCH + (tid & 1) * (NF4 + 1)] =
            float4{0.f, 0.f, 0.f, 0.f};

    const int c = tid;                        // f4 column owned by this lane
    const bool pl = (c > 0), pr = (c < NF4 - 1);
    const float4 zero4 = {0.f, 0.f, 0.f, 0.f};

    float4 hx[8];    // h-conv(x) ring: row (R0-8+s-8+i) at slot (s+i)&7
    float4 h2r[8];   // h-conv(d^2) ring, same phase pattern

    // prologue prefetch: xc for step 0 (row R0-8)
    float4 xc_pf = zero4;
    if (R0 - 8 >= 0)
        xc_pf = reinterpret_cast<const float4*>(xb + (size_t)(R0 - 8) * HW)[c];

#pragma unroll 1
    for (int rb = 0; rb < NSTEP; rb += 8) {
#pragma unroll
        for (int pp = 0; pp < 8; ++pp) {
            const int s = rb + pp;            // pp == s & 7
            const int r = R0 - 8 + s;         // row loaded this step

            // ---- stage A: hv = h-conv of x row r (0 outside image) ----
            float4 hv = zero4;
            const float4 xc = xc_pf;
            if (r >= 0 && r < HW) {
                const float4* row =
                    reinterpret_cast<const float4*>(xb + (size_t)r * HW);
                float4 xl = pl ? row[c - 1] : zero4;  // L1 hits (same lines)
                float4 xr = pr ? row[c + 1] : zero4;
                hv = conv9_3(xl, xc, xr, w);
            }

            // ---- prefetch next step's xc (row r+1), in flight across barrier
            {
                const int rn = r + 1;
                xc_pf = (rn >= 0 && rn < HW)
                    ? reinterpret_cast<const float4*>(xb + (size_t)rn * HW)[c]
                    : zero4;
            }

            // ---- stage B: mean(rd) from ring + hv; d = x - mean -> LDS ----
            float4 d4 = zero4;
            if (s >= 8) {
                const int rd = r - 4;
                if (rd >= 0 && rd < HW) {
                    float4 mean;
                    mean.x = w[8] * hv.x; mean.y = w[8] * hv.y;
                    mean.z = w[8] * hv.z; mean.w = w[8] * hv.w;
#pragma unroll
                    for (int i = 0; i < 8; ++i) {
                        // hx(rd-4+i) = hx(r-8+i) at slot (s+i)&7
                        const float4 h = hx[(pp + i) & 7];
                        mean.x = fmaf(w[i], h.x, mean.x);
                        mean.y = fmaf(w[i], h.y, mean.y);
                        mean.z = fmaf(w[i], h.z, mean.z);
                        mean.w = fmaf(w[i], h.w, mean.w);
                    }
                    float4 xm = reinterpret_cast<const float4*>(
                        xb + (size_t)rd * HW)[c];           // L1/L2 hit
                    d4.x = xm.x - mean.x; d4.y = xm.y - mean.y;
                    d4.z = xm.z - mean.z; d4.w = xm.w - mean.w;
                }
                dring[pp * DPITCH + 1 + c] = d4;            // slot s&7
            }
            hx[pp] = hv;  // overwrite row r-8 (already consumed by B)

            // ---- lgkm-only barrier: d-ring visible, vmcnt NOT drained ----
            asm volatile("s_waitcnt lgkmcnt(0)" ::: "memory");
            __builtin_amdgcn_s_barrier();
            asm volatile("" ::: "memory");

            // ---- stage C: h2v = h-conv(d(rd)^2), neighbors from LDS ----
            float4 h2v = zero4;
            if (s >= 8) {
                const float4* dr = &dring[pp * DPITCH];
                float4 dl = dr[c];        // col c-1 (pad gives zero at edge)
                float4 drr = dr[c + 2];   // col c+1
                h2v = conv9_3(sq4(dl), sq4(d4), sq4(drr), w);
            }

            // ---- stage D: n2(ro) from ring + h2v; normalize; store ----
            if (s >= 16) {
                float4 n2;
                n2.x = w[8] * h2v.x; n2.y = w[8] * h2v.y;
                n2.z = w[8] * h2v.z; n2.w = w[8] * h2v.w;
#pragma unroll
                for (int i = 0; i < 8; ++i) {
                    // h2(ro-4+i) = h2(r-12+i) at slot (s+i)&7
                    const float4 h = h2r[(pp + i) & 7];
                    n2.x = fmaf(w[i], h.x, n2.x);
                    n2.y = fmaf(w[i], h.y, n2.y);
                    n2.z = fmaf(w[i], h.z, n2.z);
                    n2.w = fmaf(w[i], h.w, n2.w);
                }
                const int ro = r - 8;                       // in [R0, R0+16)
                // d(ro) written at step s-4 -> slot (s+4)&7
                float4 dv = dring[((pp + 4) & 7) * DPITCH + 1 + c];
                float4 o;  // keep <=> sqrt(n2) > 0.5 <=> n2 > 0.25
                o.x = (n2.x > 0.25f) ? dv.x * rsqrtf(n2.x) : dv.x;
                o.y = (n2.y > 0.25f) ? dv.y * rsqrtf(n2.y) : dv.y;
                o.z = (n2.z > 0.25f) ? dv.z * rsqrtf(n2.z) : dv.z;
                o.w = (n2.w > 0.25f) ? dv.w * rsqrtf(n2.w) : dv.w;
                reinterpret_cast<float4*>(ob + (size_t)ro * HW)[c] = o;
            }
            h2r[pp] = h2v;  // overwrite row r-12 (already consumed by D)
        }
    }
}

static W9 make_w() {
    // reference: sigmah = 9/6, exponent divides by 2*sigmah = 3.0;
    // taps centered at 4.5 (asymmetric), separable: w1 = g1 / sum(g1).
    double g[9], sum = 0.0;
    for (int i = 0; i < 9; ++i) {
        double off = (double)i - 4.5;
        g[i] = exp(-(off * off) / 3.0);
        sum += g[i];
    }
    W9 r;
    for (int i = 0; i < 9; ++i) r.w[i] = (float)(g[i] / sum);
    return r;
}

extern "C" void kernel_launch(void* const* d_in, const int* in_sizes, int n_in,
                              void* d_out, int out_size, void* d_ws, size_t ws_size,
                              hipStream_t stream) {
    const float* x = (const float*)d_in[0];
    float* out = (float*)d_out;
    W9 w = make_w();
    // 64 images x 32 strips of 16 rows = 2048 blocks, 128 threads each.
    lcn_kernel<<<dim3(2048), dim3(128), 0, stream>>>(x, out, w);
}

// Round 6
// 82.936 us; speedup vs baseline: 1.2204x; 1.2204x over previous
//
#include <hip/hip_runtime.h>
#include <cmath>

// Local contrast normalization — barrier-free wave-streaming version.
// x: [64,512,512,1] f32; 9x9 Gaussian (separable, center 4.5), SAME zero pad;
// out = keep ? d/sqrt(conv(d^2)) : d, keep = sqrt(n2) > 0.5 <=> n2 > 0.25.
//
// One wave (64 lanes) owns a full 512-px row: 8 px = 2 float4 per lane.
// Strip = 16 output rows, 32 pipeline steps (rows R0-8 .. R0+23).
// NO LDS, NO barriers. Horizontal d-halo (+-4 px) via intra-wave shuffles.
// Rings in registers, all indices static:
//   hx[8] (+current = 9 taps), h2[8] (+current), d[4] (output-row delay).

struct W9 { float w[9]; };

#define HW    512
#define SROWS 16

__device__ __forceinline__ float4 f4scale(float s, float4 a) {
    return float4{s * a.x, s * a.y, s * a.z, s * a.w};
}
__device__ __forceinline__ float4 f4fma(float s, float4 a, float4 acc) {
    return float4{fmaf(s, a.x, acc.x), fmaf(s, a.y, acc.y),
                  fmaf(s, a.z, acc.z), fmaf(s, a.w, acc.w)};
}

// 9-tap conv over a 16-float window -> 8 outputs (o[k] = sum_j w[j]*X[k+j])
__device__ __forceinline__ void conv9_8(const float X[16], const float* w,
                                        float4& o0, float4& o1) {
    float o[8];
#pragma unroll
    for (int k = 0; k < 8; ++k) {
        float a = w[0] * X[k];
#pragma unroll
        for (int j = 1; j < 9; ++j) a = fmaf(w[j], X[k + j], a);
        o[k] = a;
    }
    o0 = float4{o[0], o[1], o[2], o[3]};
    o1 = float4{o[4], o[5], o[6], o[7]};
}

// vertical 9-tap from 8-deep ring + current row
#define VRING9(ring0, ring1, ppv, cur0, cur1, out0, out1)                \
    {                                                                    \
        out0 = f4scale(w[8], cur0);                                      \
        out1 = f4scale(w[8], cur1);                                      \
        _Pragma("unroll") for (int i_ = 0; i_ < 8; ++i_) {               \
            out0 = f4fma(w[i_], ring0[((ppv) + i_) & 7], out0);          \
            out1 = f4fma(w[i_], ring1[((ppv) + i_) & 7], out1);          \
        }                                                                \
    }

// stage A: hv = horizontal conv of x row r (zero outside image)
#define STAGE_A(r, hv0, hv1)                                             \
    {                                                                    \
        hv0 = z4; hv1 = z4;                                              \
        if ((unsigned)(r) < HW) {                                        \
            const float4* row_ =                                         \
                reinterpret_cast<const float4*>(xb + (size_t)(r) * HW);  \
            float4 a_ = pl ? row_[c2 - 1] : z4;                          \
            float4 b_ = row_[c2];                                        \
            float4 g_ = row_[c2 + 1];                                    \
            float4 e_ = pr ? row_[c2 + 2] : z4;                          \
            const float X_[16] = {a_.x, a_.y, a_.z, a_.w,                \
                                  b_.x, b_.y, b_.z, b_.w,                \
                                  g_.x, g_.y, g_.z, g_.w,                \
                                  e_.x, e_.y, e_.z, e_.w};               \
            conv9_8(X_, w, hv0, hv1);                                    \
        }                                                                \
    }

// stage B: mean(rd) = v-conv(hx ring + hv); d = x(rd) - mean (0 outside)
#define STAGE_B(ppv, rd, hv0, hv1, d0_, d1_)                             \
    {                                                                    \
        d0_ = z4; d1_ = z4;                                              \
        if ((unsigned)(rd) < HW) {                                       \
            float4 m0_, m1_;                                             \
            VRING9(hx0, hx1, ppv, hv0, hv1, m0_, m1_);                   \
            const float4* rowd_ =                                        \
                reinterpret_cast<const float4*>(xb + (size_t)(rd) * HW); \
            float4 x0_ = rowd_[c2], x1_ = rowd_[c2 + 1];                 \
            d0_ = float4{x0_.x - m0_.x, x0_.y - m0_.y,                   \
                         x0_.z - m0_.z, x0_.w - m0_.w};                  \
            d1_ = float4{x1_.x - m1_.x, x1_.y - m1_.y,                   \
                         x1_.z - m1_.z, x1_.w - m1_.w};                  \
        }                                                                \
    }

// stage C: h2v = h-conv(d^2); halo f4s via intra-wave shuffles
#define STAGE_C(d0_, d1_, h2v0, h2v1)                                    \
    {                                                                    \
        float4 dl_;                                                      \
        dl_.x = __shfl_up((d1_).x, 1);                                   \
        dl_.y = __shfl_up((d1_).y, 1);                                   \
        dl_.z = __shfl_up((d1_).z, 1);                                   \
        dl_.w = __shfl_up((d1_).w, 1);                                   \
        if (c == 0) dl_ = z4;                                            \
        float4 dr_;                                                      \
        dr_.x = __shfl_down((d0_).x, 1);                                 \
        dr_.y = __shfl_down((d0_).y, 1);                                 \
        dr_.z = __shfl_down((d0_).z, 1);                                 \
        dr_.w = __shfl_down((d0_).w, 1);                                 \
        if (c == 63) dr_ = z4;                                           \
        const float Xs_[16] = {                                          \
            dl_.x * dl_.x, dl_.y * dl_.y, dl_.z * dl_.z, dl_.w * dl_.w,  \
            (d0_).x * (d0_).x, (d0_).y * (d0_).y,                        \
            (d0_).z * (d0_).z, (d0_).w * (d0_).w,                        \
            (d1_).x * (d1_).x, (d1_).y * (d1_).y,                        \
            (d1_).z * (d1_).z, (d1_).w * (d1_).w,                        \
            dr_.x * dr_.x, dr_.y * dr_.y, dr_.z * dr_.z, dr_.w * dr_.w}; \
        conv9_8(Xs_, w, h2v0, h2v1);                                     \
    }

__global__ __launch_bounds__(64, 2) void lcn_kernel(const float* __restrict__ x,
                                                    float* __restrict__ out,
                                                    W9 wts) {
    const int c = threadIdx.x;          // lane 0..63, owns f4 cols 2c, 2c+1
    const int c2 = 2 * c;
    const bool pl = (c > 0), pr = (c < 63);

    // XCD swizzle: 2048 blocks = 8 XCDs x 256; 8 images per XCD, all 32
    // strips of an image co-resident on one XCD -> halo rows L2-shared.
    const int p = blockIdx.x;
    const int lid = (p & 7) * 256 + (p >> 3);
    const int img = lid >> 5;           // 0..63
    const int strip = lid & 31;         // 0..31
    const int R0 = strip * SROWS;

    const float* xb = x + (size_t)img * HW * HW;
    float* ob = out + (size_t)img * HW * HW;

    float w[9];
#pragma unroll
    for (int i = 0; i < 9; ++i) w[i] = wts.w[i];
    const float4 z4 = {0.f, 0.f, 0.f, 0.f};

    float4 hx0[8], hx1[8];   // h-conv(x) ring
    float4 q0[8], q1[8];     // h-conv(d^2) ring
    float4 dg0[4], dg1[4];   // d ring (4-step delay to output row)

    // ---- phase 1 (s = 0..7): stage A only; fill hx ring ----
#pragma unroll
    for (int pp = 0; pp < 8; ++pp) {
        const int r = R0 - 8 + pp;
        float4 hv0, hv1;
        STAGE_A(r, hv0, hv1);
        hx0[pp] = hv0; hx1[pp] = hv1;
    }

    // ---- phase 2 (s = 8..15): A + B + C; fill q ring and d ring ----
#pragma unroll
    for (int pp = 0; pp < 8; ++pp) {
        const int r = R0 + pp;          // s = 8+pp, ring phase = pp
        float4 hv0, hv1;
        STAGE_A(r, hv0, hv1);
        float4 d0, d1;
        STAGE_B(pp, r - 4, hv0, hv1, d0, d1);
        dg0[pp & 3] = d0; dg1[pp & 3] = d1;
        hx0[pp] = hv0; hx1[pp] = hv1;
        float4 h2v0, h2v1;
        STAGE_C(d0, d1, h2v0, h2v1);
        q0[pp] = h2v0; q1[pp] = h2v1;
    }

    // ---- phase 3 (s = 16..31): full pipeline, one output row per step ----
#pragma unroll 1
    for (int rb = 16; rb < 32; rb += 8) {
#pragma unroll
        for (int pp = 0; pp < 8; ++pp) {
            const int r = R0 - 8 + rb + pp;   // ring phase = pp
            float4 hv0, hv1;
            STAGE_A(r, hv0, hv1);
            float4 d0, d1;
            STAGE_B(pp, r - 4, hv0, hv1, d0, d1);
            // read d(ro) (written 4 steps ago) BEFORE overwriting the slot
            float4 do0 = dg0[pp & 3], do1 = dg1[pp & 3];
            dg0[pp & 3] = d0; dg1[pp & 3] = d1;
            hx0[pp] = hv0; hx1[pp] = hv1;
            float4 h2v0, h2v1;
            STAGE_C(d0, d1, h2v0, h2v1);
            // stage D: n2(ro) = v-conv(q ring + h2v); normalize; store
            {
                float4 n0, n1;
                VRING9(q0, q1, pp, h2v0, h2v1, n0, n1);
                const int ro = r - 8;          // in [R0, R0+16)
                float4 o0, o1;
                o0.x = (n0.x > 0.25f) ? do0.x * rsqrtf(n0.x) : do0.x;
                o0.y = (n0.y > 0.25f) ? do0.y * rsqrtf(n0.y) : do0.y;
                o0.z = (n0.z > 0.25f) ? do0.z * rsqrtf(n0.z) : do0.z;
                o0.w = (n0.w > 0.25f) ? do0.w * rsqrtf(n0.w) : do0.w;
                o1.x = (n1.x > 0.25f) ? do1.x * rsqrtf(n1.x) : do1.x;
                o1.y = (n1.y > 0.25f) ? do1.y * rsqrtf(n1.y) : do1.y;
                o1.z = (n1.z > 0.25f) ? do1.z * rsqrtf(n1.z) : do1.z;
                o1.w = (n1.w > 0.25f) ? do1.w * rsqrtf(n1.w) : do1.w;
                float4* rowo = reinterpret_cast<float4*>(ob + (size_t)ro * HW);
                rowo[c2] = o0;
                rowo[c2 + 1] = o1;
            }
            q0[pp] = h2v0; q1[pp] = h2v1;
        }
    }
}

static W9 make_w() {
    // reference: sigmah = 9/6, exponent divides by 2*sigmah = 3.0;
    // taps centered at 4.5 (asymmetric); separable: w1 = g1 / sum(g1).
    double g[9], sum = 0.0;
    for (int i = 0; i < 9; ++i) {
        double off = (double)i - 4.5;
        g[i] = exp(-(off * off) / 3.0);
        sum += g[i];
    }
    W9 r;
    for (int i = 0; i < 9; ++i) r.w[i] = (float)(g[i] / sum);
    return r;
}

extern "C" void kernel_launch(void* const* d_in, const int* in_sizes, int n_in,
                              void* d_out, int out_size, void* d_ws, size_t ws_size,
                              hipStream_t stream) {
    const float* x = (const float*)d_in[0];
    float* out = (float*)d_out;
    W9 w = make_w();
    // 64 images x 32 strips of 16 rows = 2048 blocks, 64 threads (1 wave) each.
    lcn_kernel<<<dim3(2048), dim3(64), 0, stream>>>(x, out, w);
}